// Round 7
// baseline (812.078 us; speedup 1.0000x reference)
//
#include <hip/hip_runtime.h>
#include <hip/hip_bf16.h>

// Self-attention fwd, B=2 H=16 S=2048 D=128, fp32 in/out, bf16 MFMA compute.
// R7: R6 pipeline + corrected V^T swizzle (16B-unit XOR by (d&7), both sides;
// staggered micro-row writes) + defer-max (T13, THR=8) + last-iter guards.
//  - 4 waves/block, QBLK=128 (2x16 q/wave), KVBLK=64, double-buffered LDS,
//    prefetch-to-regs before compute, convert+write after, 1 barrier/iter.
//  - K: 64 rows x 256B, 16B-unit XOR swizzle u^=(r&7) (unchanged from R6).
//  - V^T: 128 d-rows x 128B, natural k order: byte(k)=32*gcol+8*ks+2*r with
//    k=ks*16+4*gcol+r. Swizzle: 16B unit u -> u^(d&7).
//    read (lane g,c; dt): d=dt*16+c, b128 at 16*((2g)^ (c&7)) -> [ks0|ks1],
//    and 16*((2g+1)^(c&7)) -> [ks2|ks3]; 8 units x 8 lanes per phase. CF.
//    write (thread d4,kq; it,mi): m=(mi+(d4>>1))&3 staggers d&7 across all 8
//    values -> 16 distinct 8B offsets per b64 store. CF.
//  - QK^T swapped (A=K,B=Q) -> S^T; softmax lane-local (q=lane&15).
//  - PV via mfma_f32_16x16x16bf16_1k, P in regs.

typedef __attribute__((ext_vector_type(4))) float f32x4;
typedef __attribute__((ext_vector_type(8))) short s16x8;
typedef __attribute__((ext_vector_type(4))) short s16x4;

#define SDIM 2048
#define DDIM 128
#define QBLK 128
#define KBLK 64
#define NKT (SDIM / KBLK)

#define KT_BYTES 16384                  // 64 x 256 B (swizzled)
#define VT_BYTES 16384                  // 128 x 128 B (swizzled)
#define BUF_BYTES (KT_BYTES + VT_BYTES) // 32768
#define SMEM_BYTES (2 * BUF_BYTES)      // 65536; epilogue needs 33024

__device__ __forceinline__ short f2bf(float f) {
  union { __hip_bfloat16 b; short s; } u;
  u.b = __float2bfloat16(f);
  return u.s;
}

__global__ __launch_bounds__(256)
void attn_fwd_kernel(const float* __restrict__ qp, const float* __restrict__ kp,
                     const float* __restrict__ vp, float* __restrict__ op) {
  __shared__ alignas(128) char smem[SMEM_BYTES];
  const int tid  = threadIdx.x;
  const int wave = tid >> 6;
  const int lane = tid & 63;
  const int g    = lane >> 4;   // k-group 0..3
  const int c    = lane & 15;   // q (QK out) / d-row (PV A)
  const int qt   = blockIdx.x;
  const int bh   = blockIdx.y;
  const size_t base = (size_t)bh * SDIM * DDIM;
  const float scale = 0.088388347648318447f;  // 1/sqrt(128)

  // staging thread mapping
  const int d4  = tid & 31;   // V: f32x4 column 0..31
  const int kq8 = tid >> 5;   // V: k-quad 0..7 (block-wide)

  // ---- Q fragments: qfrag[qh][dc]: Q[q = qt*128+wave*32+qh*16+c]
  //      [d = dc*32 + g*8 + j], scaled, bf16 ----
  s16x8 qfrag[2][4];
#pragma unroll
  for (int qh = 0; qh < 2; ++qh) {
    const float* qrow =
        qp + base + (size_t)(qt * QBLK + wave * 32 + qh * 16 + c) * DDIM;
#pragma unroll
    for (int dc = 0; dc < 4; ++dc) {
      f32x4 x = *(const f32x4*)(qrow + dc * 32 + g * 8);
      f32x4 y = *(const f32x4*)(qrow + dc * 32 + g * 8 + 4);
      s16x8 q8;
      q8[0] = f2bf(x[0] * scale); q8[1] = f2bf(x[1] * scale);
      q8[2] = f2bf(x[2] * scale); q8[3] = f2bf(x[3] * scale);
      q8[4] = f2bf(y[0] * scale); q8[5] = f2bf(y[1] * scale);
      q8[6] = f2bf(y[2] * scale); q8[7] = f2bf(y[3] * scale);
      qfrag[qh][dc] = q8;
    }
  }

  f32x4 o[2][8];
#pragma unroll
  for (int qh = 0; qh < 2; ++qh)
#pragma unroll
    for (int i = 0; i < 8; ++i) o[qh][i] = (f32x4){0.f, 0.f, 0.f, 0.f};
  float mrun[2] = {-INFINITY, -INFINITY};
  float lrun[2] = {0.f, 0.f};

  const f32x4* kg0 = (const f32x4*)(kp + base);
  const f32x4* vg0 = (const f32x4*)(vp + base);

  f32x4 kpre[8], vpre[8];

  auto LOADR = [&](int kt2) {
    const f32x4* kg = kg0 + (size_t)kt2 * KBLK * (DDIM / 4);
    const f32x4* vg = vg0 + (size_t)kt2 * KBLK * (DDIM / 4);
#pragma unroll
    for (int pi = 0; pi < 4; ++pi) {
      const int pair = tid + pi * 256;          // 0..1023 (16B-pairs)
      const int r = pair >> 4, p = pair & 15;
      kpre[2 * pi]     = kg[r * 32 + 2 * p];
      kpre[2 * pi + 1] = kg[r * 32 + 2 * p + 1];
    }
#pragma unroll
    for (int it = 0; it < 2; ++it) {
      const int kb = 4 * (kq8 + 8 * it);
#pragma unroll
      for (int j = 0; j < 4; ++j)
        vpre[4 * it + j] = vg[(kb + j) * 32 + d4];
    }
  };

  auto CONVW = [&](char* kdst, char* vdst) {
    // K: b128 stores, 16B-unit swizzle u^=(r&7)
#pragma unroll
    for (int pi = 0; pi < 4; ++pi) {
      const int pair = tid + pi * 256;
      const int r = pair >> 4, p = pair & 15;
      f32x4 a = kpre[2 * pi], b2 = kpre[2 * pi + 1];
      s16x8 w;
      w[0] = f2bf(a[0]);  w[1] = f2bf(a[1]);
      w[2] = f2bf(a[2]);  w[3] = f2bf(a[3]);
      w[4] = f2bf(b2[0]); w[5] = f2bf(b2[1]);
      w[6] = f2bf(b2[2]); w[7] = f2bf(b2[3]);
      *(s16x8*)(kdst + (r << 8) + 16 * (p ^ (r & 7))) = w;
    }
    // V^T: 4x4 register transpose; natural k order; u^=(d&7); staggered m
#pragma unroll
    for (int it = 0; it < 2; ++it) {
      const int t  = kq8 + 8 * it;              // k-quad 0..15
      const int u  = 2 * (t & 3) + (t >> 3);    // 16B unit (logical)
      const int hb = 8 * ((t >> 2) & 1);        // 8B half within unit
#pragma unroll
      for (int mi = 0; mi < 4; ++mi) {
        const int m = (mi + (d4 >> 1)) & 3;     // stagger -> d&7 spans 0..7
        const int d = 4 * d4 + m;
        s16x4 w;
        w[0] = f2bf(vpre[4 * it + 0][m]); w[1] = f2bf(vpre[4 * it + 1][m]);
        w[2] = f2bf(vpre[4 * it + 2][m]); w[3] = f2bf(vpre[4 * it + 3][m]);
        *(s16x4*)(vdst + (d << 7) + 16 * (u ^ (d & 7)) + hb) = w;
      }
    }
  };

  // ---- prologue: stage tile 0 ----
  LOADR(0);
  CONVW(smem, smem + KT_BYTES);
  __syncthreads();
  int cur = 0;

  for (int kt = 0; kt < NKT; ++kt) {
    const bool notlast = (kt + 1 < NKT);
    if (notlast) LOADR(kt + 1);

    char* kbase = smem + cur * BUF_BYTES;
    char* vbase = kbase + KT_BYTES;

    // ---- S^T = K * Q^T : st[qh][ks][r] = S^T[k=ks*16+4g+r][q-sub qh] ----
    f32x4 st[2][4];
    const int rx = c & 7;
#pragma unroll
    for (int ks = 0; ks < 4; ++ks) {
      const char* kb_ = kbase + ((ks * 16 + c) << 8);
      s16x8 kf[4];
#pragma unroll
      for (int dc = 0; dc < 4; ++dc)
        kf[dc] = *(const s16x8*)(kb_ + 16 * ((4 * dc + g) ^ rx));
#pragma unroll
      for (int qh = 0; qh < 2; ++qh) {
        f32x4 acc = (f32x4){0.f, 0.f, 0.f, 0.f};
#pragma unroll
        for (int dc = 0; dc < 4; ++dc)
          acc = __builtin_amdgcn_mfma_f32_16x16x32_bf16(kf[dc], qfrag[qh][dc],
                                                        acc, 0, 0, 0);
        st[qh][ks] = acc;
      }
    }

    // ---- online softmax per q-sub, defer-max THR=8 (T13) ----
#pragma unroll
    for (int qh = 0; qh < 2; ++qh) {
      float tmax = st[qh][0][0];
#pragma unroll
      for (int ks = 0; ks < 4; ++ks)
#pragma unroll
        for (int r = 0; r < 4; ++r) tmax = fmaxf(tmax, st[qh][ks][r]);
      tmax = fmaxf(tmax, __shfl_xor(tmax, 16));
      tmax = fmaxf(tmax, __shfl_xor(tmax, 32));
      if (!__all(tmax <= mrun[qh] + 8.f)) {
        const float mnew  = fmaxf(mrun[qh], tmax);
        const float alpha = __expf(mrun[qh] - mnew);
        lrun[qh] *= alpha;
        mrun[qh] = mnew;
#pragma unroll
        for (int dt = 0; dt < 8; ++dt)
#pragma unroll
          for (int r = 0; r < 4; ++r) o[qh][dt][r] *= alpha;
      }
      float tsum = 0.f;
#pragma unroll
      for (int ks = 0; ks < 4; ++ks)
#pragma unroll
        for (int r = 0; r < 4; ++r) {
          const float p = __expf(st[qh][ks][r] - mrun[qh]);
          st[qh][ks][r] = p;
          tsum += p;
        }
      tsum += __shfl_xor(tsum, 16);
      tsum += __shfl_xor(tsum, 32);
      lrun[qh] += tsum;
    }

    // ---- O^T += V^T * P^T ----
    s16x4 pf[4][2];
#pragma unroll
    for (int ks = 0; ks < 4; ++ks)
#pragma unroll
      for (int qh = 0; qh < 2; ++qh) {
        s16x4 p4;
        p4[0] = f2bf(st[qh][ks][0]); p4[1] = f2bf(st[qh][ks][1]);
        p4[2] = f2bf(st[qh][ks][2]); p4[3] = f2bf(st[qh][ks][3]);
        pf[ks][qh] = p4;
      }
    const int c7 = c & 7;
#pragma unroll
    for (int dt = 0; dt < 8; ++dt) {
      const int d = dt * 16 + c;                 // d&7 == c&7
      const char* vb = vbase + (d << 7);
      s16x8 v8a = *(const s16x8*)(vb + 16 * ((2 * g) ^ c7));      // [ks0|ks1]
      s16x8 v8b = *(const s16x8*)(vb + 16 * ((2 * g + 1) ^ c7));  // [ks2|ks3]
      s16x4 vf0 = __builtin_shufflevector(v8a, v8a, 0, 1, 2, 3);
      s16x4 vf1 = __builtin_shufflevector(v8a, v8a, 4, 5, 6, 7);
      s16x4 vf2 = __builtin_shufflevector(v8b, v8b, 0, 1, 2, 3);
      s16x4 vf3 = __builtin_shufflevector(v8b, v8b, 4, 5, 6, 7);
      o[0][dt] = __builtin_amdgcn_mfma_f32_16x16x16bf16_1k(vf0, pf[0][0], o[0][dt], 0, 0, 0);
      o[1][dt] = __builtin_amdgcn_mfma_f32_16x16x16bf16_1k(vf0, pf[0][1], o[1][dt], 0, 0, 0);
      o[0][dt] = __builtin_amdgcn_mfma_f32_16x16x16bf16_1k(vf1, pf[1][0], o[0][dt], 0, 0, 0);
      o[1][dt] = __builtin_amdgcn_mfma_f32_16x16x16bf16_1k(vf1, pf[1][1], o[1][dt], 0, 0, 0);
      o[0][dt] = __builtin_amdgcn_mfma_f32_16x16x16bf16_1k(vf2, pf[2][0], o[0][dt], 0, 0, 0);
      o[1][dt] = __builtin_amdgcn_mfma_f32_16x16x16bf16_1k(vf2, pf[2][1], o[1][dt], 0, 0, 0);
      o[0][dt] = __builtin_amdgcn_mfma_f32_16x16x16bf16_1k(vf3, pf[3][0], o[0][dt], 0, 0, 0);
      o[1][dt] = __builtin_amdgcn_mfma_f32_16x16x16bf16_1k(vf3, pf[3][1], o[1][dt], 0, 0, 0);
    }

    // ---- write prefetched tile to alternate buffer; single barrier ----
    if (notlast) {
      CONVW(smem + (cur ^ 1) * BUF_BYTES,
            smem + (cur ^ 1) * BUF_BYTES + KT_BYTES);
      __syncthreads();
      cur ^= 1;
    }
  }

  // ---- epilogue: normalize, transpose O^T->O via LDS (two passes) ----
  float* olds = (float*)smem;
  float* orow = op + base + (size_t)qt * QBLK * DDIM;
#pragma unroll
  for (int qh = 0; qh < 2; ++qh) {
    __syncthreads();
    const float invl = 1.f / lrun[qh];
#pragma unroll
    for (int dt = 0; dt < 8; ++dt)
#pragma unroll
      for (int r = 0; r < 4; ++r)
        olds[(wave * 16 + c) * 129 + dt * 16 + g * 4 + r] = o[qh][dt][r] * invl;
    __syncthreads();
#pragma unroll 4
    for (int i = 0; i < 32; ++i) {
      const int idx = tid + i * 256;        // 8192 floats
      const int lr = idx >> 7, d = idx & 127;
      const int q = (lr >> 4) * 32 + qh * 16 + (lr & 15);
      orow[q * DDIM + d] = olds[lr * 129 + d];
    }
  }
}

extern "C" void kernel_launch(void* const* d_in, const int* in_sizes, int n_in,
                              void* d_out, int out_size, void* d_ws, size_t ws_size,
                              hipStream_t stream) {
  const float* q = (const float*)d_in[0];
  const float* k = (const float*)d_in[1];
  const float* v = (const float*)d_in[2];
  float* out = (float*)d_out;
  dim3 grid(SDIM / QBLK, 2 * 16);   // (q-tiles, B*H)
  attn_fwd_kernel<<<grid, 256, 0, stream>>>(q, k, v, out);
}

// Round 8
// 324.048 us; speedup vs baseline: 2.5060x; 2.5060x over previous
//
#include <hip/hip_runtime.h>
#include <hip/hip_bf16.h>

// Self-attention fwd, B=2 H=16 S=2048 D=128, fp32 in/out, bf16 MFMA compute.
// R8 = R6 skeleton (198us measured) + corrected STATIC V^T swizzle + defer-max.
//  - 4 waves/block, QBLK=128 (2x16 q/wave), KVBLK=64, double-buffered LDS,
//    prefetch-to-regs before compute, convert+write after, 1 barrier/iter.
//  - K: 64 rows x 256B, 16B-unit XOR swizzle u^=(r&7) (R6, verified).
//  - V^T: 128 d-rows x 128B = 16 8B-slots; k-quad q (k=4q..4q+3, natural
//    order) stored at slot q^(d&15).
//    write (thread d4,kq8; it,mi): d=4*d4+mi (mi STATIC), q=kq8+8it,
//      addr=(d<<7)+8*(q^(d&15)). 8 slots/wave-store -> 2x conflict (writes only).
//    read (lane g,c; dt,ks): d=16*dt+c, q=4*ks+g, addr=(d<<7)+8*((4ks+g)^c);
//      slots span all 16 across wave -> b64 floor, conflict-free.
//    vf[r]=V[k=16ks+4g+r][d] matches pf[r]=P[k=16ks+4g+r] (same k-map). 
//  - QK^T swapped (A=K,B=Q) -> S^T; softmax lane-local (q=lane&15), T13
//    defer-max THR=8 (lrun <= 2048*e^8 ~ 6e6, fp32-safe).
//  - PV via mfma_f32_16x16x16bf16_1k, P in regs.
// RULE #20 GUARD: no runtime indexing into ext_vector types anywhere.

typedef __attribute__((ext_vector_type(4))) float f32x4;
typedef __attribute__((ext_vector_type(8))) short s16x8;
typedef __attribute__((ext_vector_type(4))) short s16x4;

#define SDIM 2048
#define DDIM 128
#define QBLK 128
#define KBLK 64
#define NKT (SDIM / KBLK)

#define KT_BYTES 16384                  // 64 x 256 B (swizzled)
#define VT_BYTES 16384                  // 128 x 128 B (swizzled)
#define BUF_BYTES (KT_BYTES + VT_BYTES) // 32768
#define SMEM_BYTES (2 * BUF_BYTES)      // 65536; epilogue needs 33024

__device__ __forceinline__ short f2bf(float f) {
  union { __hip_bfloat16 b; short s; } u;
  u.b = __float2bfloat16(f);
  return u.s;
}

__global__ __launch_bounds__(256)
void attn_fwd_kernel(const float* __restrict__ qp, const float* __restrict__ kp,
                     const float* __restrict__ vp, float* __restrict__ op) {
  __shared__ alignas(128) char smem[SMEM_BYTES];
  const int tid  = threadIdx.x;
  const int wave = tid >> 6;
  const int lane = tid & 63;
  const int g    = lane >> 4;   // k-group 0..3
  const int c    = lane & 15;   // q (QK out) / d-row (PV A)
  const int qt   = blockIdx.x;
  const int bh   = blockIdx.y;
  const size_t base = (size_t)bh * SDIM * DDIM;
  const float scale = 0.088388347648318447f;  // 1/sqrt(128)

  // staging thread mapping
  const int d4  = tid & 31;   // V: f32x4 column 0..31
  const int kq8 = tid >> 5;   // V: k-quad 0..7 (block-wide)

  // ---- Q fragments: qfrag[qh][dc]: Q[q = qt*128+wave*32+qh*16+c]
  //      [d = dc*32 + g*8 + j], scaled, bf16 ----
  s16x8 qfrag[2][4];
#pragma unroll
  for (int qh = 0; qh < 2; ++qh) {
    const float* qrow =
        qp + base + (size_t)(qt * QBLK + wave * 32 + qh * 16 + c) * DDIM;
#pragma unroll
    for (int dc = 0; dc < 4; ++dc) {
      f32x4 x = *(const f32x4*)(qrow + dc * 32 + g * 8);
      f32x4 y = *(const f32x4*)(qrow + dc * 32 + g * 8 + 4);
      s16x8 q8;
      q8[0] = f2bf(x[0] * scale); q8[1] = f2bf(x[1] * scale);
      q8[2] = f2bf(x[2] * scale); q8[3] = f2bf(x[3] * scale);
      q8[4] = f2bf(y[0] * scale); q8[5] = f2bf(y[1] * scale);
      q8[6] = f2bf(y[2] * scale); q8[7] = f2bf(y[3] * scale);
      qfrag[qh][dc] = q8;
    }
  }

  f32x4 o[2][8];
#pragma unroll
  for (int qh = 0; qh < 2; ++qh)
#pragma unroll
    for (int i = 0; i < 8; ++i) o[qh][i] = (f32x4){0.f, 0.f, 0.f, 0.f};
  float mrun[2] = {-INFINITY, -INFINITY};
  float lrun[2] = {0.f, 0.f};

  const f32x4* kg0 = (const f32x4*)(kp + base);
  const f32x4* vg0 = (const f32x4*)(vp + base);

  f32x4 kpre[8], vpre[8];

  auto LOADR = [&](int kt2) {
    const f32x4* kg = kg0 + (size_t)kt2 * KBLK * (DDIM / 4);
    const f32x4* vg = vg0 + (size_t)kt2 * KBLK * (DDIM / 4);
#pragma unroll
    for (int pi = 0; pi < 4; ++pi) {
      const int pair = tid + pi * 256;          // 0..1023 (16B-pairs)
      const int r = pair >> 4, p = pair & 15;
      kpre[2 * pi]     = kg[r * 32 + 2 * p];
      kpre[2 * pi + 1] = kg[r * 32 + 2 * p + 1];
    }
#pragma unroll
    for (int it = 0; it < 2; ++it) {
      const int kb = 4 * (kq8 + 8 * it);
#pragma unroll
      for (int j = 0; j < 4; ++j)
        vpre[4 * it + j] = vg[(kb + j) * 32 + d4];
    }
  };

  auto CONVW = [&](char* kdst, char* vdst) {
    // K: b128 stores, 16B-unit swizzle u^=(r&7)
#pragma unroll
    for (int pi = 0; pi < 4; ++pi) {
      const int pair = tid + pi * 256;
      const int r = pair >> 4, p = pair & 15;
      f32x4 a = kpre[2 * pi], b2 = kpre[2 * pi + 1];
      s16x8 w;
      w[0] = f2bf(a[0]);  w[1] = f2bf(a[1]);
      w[2] = f2bf(a[2]);  w[3] = f2bf(a[3]);
      w[4] = f2bf(b2[0]); w[5] = f2bf(b2[1]);
      w[6] = f2bf(b2[2]); w[7] = f2bf(b2[3]);
      *(s16x8*)(kdst + (r << 8) + 16 * (p ^ (r & 7))) = w;
    }
    // V^T: 4x4 register transpose, STATIC mi; slot q^(d&15)
#pragma unroll
    for (int it = 0; it < 2; ++it) {
      const int q = kq8 + 8 * it;               // k-quad 0..15
#pragma unroll
      for (int mi = 0; mi < 4; ++mi) {
        const int d = 4 * d4 + mi;
        s16x4 w;
        w[0] = f2bf(vpre[4 * it + 0][mi]); w[1] = f2bf(vpre[4 * it + 1][mi]);
        w[2] = f2bf(vpre[4 * it + 2][mi]); w[3] = f2bf(vpre[4 * it + 3][mi]);
        *(s16x4*)(vdst + (d << 7) + 8 * (q ^ (d & 15))) = w;
      }
    }
  };

  // ---- prologue: stage tile 0 ----
  LOADR(0);
  CONVW(smem, smem + KT_BYTES);
  __syncthreads();
  int cur = 0;

  for (int kt = 0; kt < NKT; ++kt) {
    // prefetch next tile (clamped on last iter; harmless redo, keeps
    // loads unconditional for the scheduler)
    const int ktn = (kt + 1 < NKT) ? kt + 1 : kt;
    LOADR(ktn);

    char* kbase = smem + cur * BUF_BYTES;
    char* vbase = kbase + KT_BYTES;

    // ---- S^T = K * Q^T : st[qh][ks][r] = S^T[k=ks*16+4g+r][q-sub qh] ----
    f32x4 st[2][4];
    const int rx = c & 7;
#pragma unroll
    for (int ks = 0; ks < 4; ++ks) {
      const char* kb_ = kbase + ((ks * 16 + c) << 8);
      s16x8 kf[4];
#pragma unroll
      for (int dc = 0; dc < 4; ++dc)
        kf[dc] = *(const s16x8*)(kb_ + 16 * ((4 * dc + g) ^ rx));
#pragma unroll
      for (int qh = 0; qh < 2; ++qh) {
        f32x4 acc = (f32x4){0.f, 0.f, 0.f, 0.f};
#pragma unroll
        for (int dc = 0; dc < 4; ++dc)
          acc = __builtin_amdgcn_mfma_f32_16x16x32_bf16(kf[dc], qfrag[qh][dc],
                                                        acc, 0, 0, 0);
        st[qh][ks] = acc;
      }
    }

    // ---- online softmax per q-sub, defer-max THR=8 (T13) ----
#pragma unroll
    for (int qh = 0; qh < 2; ++qh) {
      float tmax = st[qh][0][0];
#pragma unroll
      for (int ks = 0; ks < 4; ++ks)
#pragma unroll
        for (int r = 0; r < 4; ++r) tmax = fmaxf(tmax, st[qh][ks][r]);
      tmax = fmaxf(tmax, __shfl_xor(tmax, 16));
      tmax = fmaxf(tmax, __shfl_xor(tmax, 32));
      if (!__all(tmax <= mrun[qh] + 8.f)) {
        const float mnew  = fmaxf(mrun[qh], tmax);
        const float alpha = __expf(mrun[qh] - mnew);
        lrun[qh] *= alpha;
        mrun[qh] = mnew;
#pragma unroll
        for (int dt = 0; dt < 8; ++dt)
#pragma unroll
          for (int r = 0; r < 4; ++r) o[qh][dt][r] *= alpha;
      }
      float tsum = 0.f;
#pragma unroll
      for (int ks = 0; ks < 4; ++ks)
#pragma unroll
        for (int r = 0; r < 4; ++r) {
          const float p = __expf(st[qh][ks][r] - mrun[qh]);
          st[qh][ks][r] = p;
          tsum += p;
        }
      tsum += __shfl_xor(tsum, 16);
      tsum += __shfl_xor(tsum, 32);
      lrun[qh] += tsum;
    }

    // ---- O^T += V^T * P^T ----
    s16x4 pf[4][2];
#pragma unroll
    for (int ks = 0; ks < 4; ++ks)
#pragma unroll
      for (int qh = 0; qh < 2; ++qh) {
        s16x4 p4;
        p4[0] = f2bf(st[qh][ks][0]); p4[1] = f2bf(st[qh][ks][1]);
        p4[2] = f2bf(st[qh][ks][2]); p4[3] = f2bf(st[qh][ks][3]);
        pf[ks][qh] = p4;
      }
#pragma unroll
    for (int dt = 0; dt < 8; ++dt) {
      const int d = dt * 16 + c;                 // d&15 == c
      const char* vb = vbase + (d << 7);
      s16x4 vf0 = *(const s16x4*)(vb + 8 * ((4 * 0 + g) ^ c));
      s16x4 vf1 = *(const s16x4*)(vb + 8 * ((4 * 1 + g) ^ c));
      s16x4 vf2 = *(const s16x4*)(vb + 8 * ((4 * 2 + g) ^ c));
      s16x4 vf3 = *(const s16x4*)(vb + 8 * ((4 * 3 + g) ^ c));
      o[0][dt] = __builtin_amdgcn_mfma_f32_16x16x16bf16_1k(vf0, pf[0][0], o[0][dt], 0, 0, 0);
      o[1][dt] = __builtin_amdgcn_mfma_f32_16x16x16bf16_1k(vf0, pf[0][1], o[1][dt], 0, 0, 0);
      o[0][dt] = __builtin_amdgcn_mfma_f32_16x16x16bf16_1k(vf1, pf[1][0], o[0][dt], 0, 0, 0);
      o[1][dt] = __builtin_amdgcn_mfma_f32_16x16x16bf16_1k(vf1, pf[1][1], o[1][dt], 0, 0, 0);
      o[0][dt] = __builtin_amdgcn_mfma_f32_16x16x16bf16_1k(vf2, pf[2][0], o[0][dt], 0, 0, 0);
      o[1][dt] = __builtin_amdgcn_mfma_f32_16x16x16bf16_1k(vf2, pf[2][1], o[1][dt], 0, 0, 0);
      o[0][dt] = __builtin_amdgcn_mfma_f32_16x16x16bf16_1k(vf3, pf[3][0], o[0][dt], 0, 0, 0);
      o[1][dt] = __builtin_amdgcn_mfma_f32_16x16x16bf16_1k(vf3, pf[3][1], o[1][dt], 0, 0, 0);
    }

    // ---- write prefetched tile to alternate buffer; single barrier ----
    CONVW(smem + (cur ^ 1) * BUF_BYTES,
          smem + (cur ^ 1) * BUF_BYTES + KT_BYTES);
    __syncthreads();
    cur ^= 1;
  }

  // ---- epilogue: normalize, transpose O^T->O via LDS (two passes) ----
  float* olds = (float*)smem;
  float* orow = op + base + (size_t)qt * QBLK * DDIM;
#pragma unroll
  for (int qh = 0; qh < 2; ++qh) {
    __syncthreads();
    const float invl = 1.f / lrun[qh];
#pragma unroll
    for (int dt = 0; dt < 8; ++dt)
#pragma unroll
      for (int r = 0; r < 4; ++r)
        olds[(wave * 16 + c) * 129 + dt * 16 + g * 4 + r] = o[qh][dt][r] * invl;
    __syncthreads();
#pragma unroll 4
    for (int i = 0; i < 32; ++i) {
      const int idx = tid + i * 256;        // 8192 floats
      const int lr = idx >> 7, d = idx & 127;
      const int q = (lr >> 4) * 32 + qh * 16 + (lr & 15);
      orow[q * DDIM + d] = olds[lr * 129 + d];
    }
  }
}

extern "C" void kernel_launch(void* const* d_in, const int* in_sizes, int n_in,
                              void* d_out, int out_size, void* d_ws, size_t ws_size,
                              hipStream_t stream) {
  const float* q = (const float*)d_in[0];
  const float* k = (const float*)d_in[1];
  const float* v = (const float*)d_in[2];
  float* out = (float*)d_out;
  dim3 grid(SDIM / QBLK, 2 * 16);   // (q-tiles, B*H)
  attn_fwd_kernel<<<grid, 256, 0, stream>>>(q, k, v, out);
}